// Round 15
// baseline (22.099 us; speedup 1.0000x reference)
//
#include <hip/hip_runtime.h>

#define H 512
#define W 512

typedef float f32x4 __attribute__((ext_vector_type(4)));

// DPP wave rotates: *_ror moves data toward HIGHER lanes (dst[i]=src[i-1]).
__device__ __forceinline__ float dpp_ror1(float v) {   // dst[i] = src[(i-1) & 63]
    return __int_as_float(__builtin_amdgcn_update_dpp(
        0, __float_as_int(v), 0x13C /*wave_ror:1*/, 0xF, 0xF, false));
}
__device__ __forceinline__ float dpp_rol1(float v) {   // dst[i] = src[(i+1) & 63]
    return __int_as_float(__builtin_amdgcn_update_dpp(
        0, __float_as_int(v), 0x134 /*wave_rol:1*/, 0xF, 0xF, false));
}

// R6 schedule (4 output rows/wave, keep[3], one-ahead tail) + R13 dense layout
// (lane owns chunkA=[4L,4L+4), chunkB=[256+4L,+4); every load/store is a
// contiguous 1KB wave access). 1536 blocks, 6144 waves.
__global__ __launch_bounds__(256, 4) void lvar_kernel(const float* __restrict__ x,
                                                      float* __restrict__ out) {
    const int lane = threadIdx.x;                 // 0..63
    const int wv   = threadIdx.y;                 // 0..3
    const int bid  = blockIdx.x;
    const int wg   = (bid & 7) * 192 + (bid >> 3);// XCD-bijective (1536 % 8 == 0)
    const int img  = wg >> 5;                     // 0..47
    const int band = wg & 31;                     // 16-row band
    const int R    = band * 16 + wv * 4;          // this wave's first output row

    const float* __restrict__ xim = x + (size_t)img * (H * W);
    float* __restrict__ oim = out + (size_t)img * (H * W);
    const int c4 = lane * 4;
    const bool is0  = (lane == 0);
    const bool is63 = (lane == 63);
    const float inv = 1.0f / 49.0f;

    auto loadrow = [&](int r, float v[8]) {       // v[0..3]=chunkA, v[4..7]=chunkB
        const int gr = r & (H - 1);
        const float* rowp = xim + gr * W;
        const f32x4 a = *(const f32x4*)(rowp + c4);         // dense 1KB wave access
        const f32x4 b = *(const f32x4*)(rowp + 256 + c4);   // dense 1KB wave access
        v[0]=a.x; v[1]=a.y; v[2]=a.z; v[3]=a.w;
        v[4]=b.x; v[5]=b.y; v[6]=b.z; v[7]=b.w;
    };

    float s[8], q[8];
    #pragma unroll
    for (int c = 0; c < 8; ++c) { s[c] = 0.f; q[c] = 0.f; }

    auto acc = [&](const float v[8]) {
        #pragma unroll
        for (int c = 0; c < 8; ++c) {
            s[c] += v[c];
            q[c] = fmaf(v[c], v[c], q[c]);
        }
    };
    auto update = [&](const float nv[8], const float old[8]) {
        #pragma unroll
        for (int c = 0; c < 8; ++c) {
            s[c] += nv[c] - old[c];
            q[c] = fmaf(nv[c], nv[c], q[c]);
            q[c] = fmaf(-old[c], old[c], q[c]);
        }
    };

    auto emit = [&](int r) {
        // 10-wide windows per chunk: [pred(3) | own(4) | succ(3)]
        float WA[10], QA[10], WB[10], QB[10];
        #pragma unroll
        for (int j = 1; j <= 3; ++j) {            // predecessors
            const float rAs = dpp_ror1(s[j]),     rBs = dpp_ror1(s[4 + j]);
            const float rAq = dpp_ror1(q[j]),     rBq = dpp_ror1(q[4 + j]);
            WA[j - 1] = is0 ? rBs : rAs;          // pred(A_0) = B_63
            WB[j - 1] = is0 ? rAs : rBs;          // pred(B_0) = A_63
            QA[j - 1] = is0 ? rBq : rAq;
            QB[j - 1] = is0 ? rAq : rBq;
        }
        #pragma unroll
        for (int j = 0; j < 4; ++j) {
            WA[3 + j] = s[j];     QA[3 + j] = q[j];
            WB[3 + j] = s[4 + j]; QB[3 + j] = q[4 + j];
        }
        #pragma unroll
        for (int j = 0; j <= 2; ++j) {            // successors
            const float rAs = dpp_rol1(s[j]),     rBs = dpp_rol1(s[4 + j]);
            const float rAq = dpp_rol1(q[j]),     rBq = dpp_rol1(q[4 + j]);
            WA[7 + j] = is63 ? rBs : rAs;         // succ(A_63) = B_0
            WB[7 + j] = is63 ? rAs : rBs;         // succ(B_63) = A_0 (wrap mod 512)
            QA[7 + j] = is63 ? rBq : rAq;
            QB[7 + j] = is63 ? rAq : rBq;
        }

        float res[8];
        {   // chunkA outputs
            float hs = WA[0]+WA[1]+WA[2]+WA[3]+WA[4]+WA[5]+WA[6];
            float hq = QA[0]+QA[1]+QA[2]+QA[3]+QA[4]+QA[5]+QA[6];
            { const float m = hs * inv; res[0] = fmaf(-m, m, hq * inv); }
            #pragma unroll
            for (int k = 1; k < 4; ++k) {
                hs += WA[k + 6] - WA[k - 1];
                hq += QA[k + 6] - QA[k - 1];
                const float m = hs * inv;
                res[k] = fmaf(-m, m, hq * inv);
            }
        }
        {   // chunkB outputs
            float hs = WB[0]+WB[1]+WB[2]+WB[3]+WB[4]+WB[5]+WB[6];
            float hq = QB[0]+QB[1]+QB[2]+QB[3]+QB[4]+QB[5]+QB[6];
            { const float m = hs * inv; res[4] = fmaf(-m, m, hq * inv); }
            #pragma unroll
            for (int k = 1; k < 4; ++k) {
                hs += WB[k + 6] - WB[k - 1];
                hq += QB[k + 6] - QB[k - 1];
                const float m = hs * inv;
                res[4 + k] = fmaf(-m, m, hq * inv);
            }
        }
        float* rowp = oim + r * W;
        f32x4 oA = {res[0], res[1], res[2], res[3]};
        f32x4 oB = {res[4], res[5], res[6], res[7]};
        __builtin_nontemporal_store(oA, (f32x4*)(rowp + c4));        // dense
        __builtin_nontemporal_store(oB, (f32x4*)(rowp + 256 + c4));  // dense
    };

    // ---- init: burst rows R-3..R+3 (keep first 3 for subtraction) ----
    float keep[3][8];
    float t0[8], t1[8], t2[8], t3[8];
    loadrow(R - 3, keep[0]); loadrow(R - 2, keep[1]); loadrow(R - 1, keep[2]);
    loadrow(R + 0, t0); loadrow(R + 1, t1); loadrow(R + 2, t2); loadrow(R + 3, t3);
    acc(keep[0]); acc(keep[1]); acc(keep[2]);
    acc(t0); acc(t1); acc(t2); acc(t3);           // t0..t3 die here

    // ---- 4 output rows; tail loads one emit ahead, double-buffered ----
    float va[8], vb[8];
    loadrow(R + 4, va);
    emit(R);
    loadrow(R + 5, vb);
    update(va, keep[0]); emit(R + 1);
    loadrow(R + 6, va);
    update(vb, keep[1]); emit(R + 2);
    update(va, keep[2]); emit(R + 3);
}

extern "C" void kernel_launch(void* const* d_in, const int* in_sizes, int n_in,
                              void* d_out, int out_size, void* d_ws, size_t ws_size,
                              hipStream_t stream) {
    const float* x = (const float*)d_in[0];
    float* out = (float*)d_out;
    const int nimg = in_sizes[0] / (H * W);       // 48
    dim3 grid(nimg * 32);                         // 1536 blocks (8 | 1536)
    dim3 block(64, 4);
    lvar_kernel<<<grid, block, 0, stream>>>(x, out);
}

// Round 16
// 21.065 us; speedup vs baseline: 1.0491x; 1.0491x over previous
//
#include <hip/hip_runtime.h>

#define H 512
#define W 512

typedef float f32x4 __attribute__((ext_vector_type(4)));

// DPP wave rotates: *_ror moves data toward HIGHER lanes (dst[i]=src[i-1]).
__device__ __forceinline__ float dpp_ror1(float v) {   // dst[i] = src[(i-1) & 63]
    return __int_as_float(__builtin_amdgcn_update_dpp(
        0, __float_as_int(v), 0x13C /*wave_ror:1*/, 0xF, 0xF, false));
}
__device__ __forceinline__ float dpp_rol1(float v) {   // dst[i] = src[(i+1) & 63]
    return __int_as_float(__builtin_amdgcn_update_dpp(
        0, __float_as_int(v), 0x134 /*wave_rol:1*/, 0xF, 0xF, false));
}

// Exactly R13 (2 output rows/wave, 8-row upfront burst, dense chunk layout)
// with ONE change: plain stores instead of nontemporal. Output write-allocates
// in L2/L3 (100MB working set < 256MB L3) instead of being forced to HBM
// inside the timed window.
__global__ __launch_bounds__(256, 4) void lvar_kernel(const float* __restrict__ x,
                                                      float* __restrict__ out) {
    const int lane = threadIdx.x;                 // 0..63
    const int wv   = threadIdx.y;                 // 0..3
    const int bid  = blockIdx.x;
    const int wg   = (bid & 7) * 384 + (bid >> 3);// XCD-bijective (3072 % 8 == 0)
    const int img  = wg >> 6;                     // 0..47
    const int band = wg & 63;                     // 8-row band
    const int R    = band * 8 + wv * 2;           // this wave's first output row

    const float* __restrict__ xim = x + (size_t)img * (H * W);
    float* __restrict__ oim = out + (size_t)img * (H * W);
    const int c4 = lane * 4;
    const bool is0  = (lane == 0);
    const bool is63 = (lane == 63);
    const float inv = 1.0f / 49.0f;

    auto loadrow = [&](int r, float v[8]) {       // v[0..3]=chunkA, v[4..7]=chunkB
        const int gr = r & (H - 1);
        const float* rowp = xim + gr * W;
        const f32x4 a = *(const f32x4*)(rowp + c4);         // dense 1KB wave access
        const f32x4 b = *(const f32x4*)(rowp + 256 + c4);   // dense 1KB wave access
        v[0]=a.x; v[1]=a.y; v[2]=a.z; v[3]=a.w;
        v[4]=b.x; v[5]=b.y; v[6]=b.z; v[7]=b.w;
    };

    // ---- burst: all 8 rows (R-3 .. R+4) issued before any consumption ----
    float r0[8], r1[8], r2[8], r3[8], r4[8], r5[8], r6[8], r7[8];
    loadrow(R - 3, r0); loadrow(R - 2, r1); loadrow(R - 1, r2); loadrow(R + 0, r3);
    loadrow(R + 1, r4); loadrow(R + 2, r5); loadrow(R + 3, r6); loadrow(R + 4, r7);

    float s[8], q[8];
    #pragma unroll
    for (int c = 0; c < 8; ++c) { s[c] = 0.f; q[c] = 0.f; }

    auto acc = [&](const float v[8]) {
        #pragma unroll
        for (int c = 0; c < 8; ++c) {
            s[c] += v[c];
            q[c] = fmaf(v[c], v[c], q[c]);
        }
    };

    auto emit = [&](int r) {
        // 10-wide windows per chunk: [pred(3) | own(4) | succ(3)]
        float WA[10], QA[10], WB[10], QB[10];
        #pragma unroll
        for (int j = 1; j <= 3; ++j) {            // predecessors
            const float rAs = dpp_ror1(s[j]),     rBs = dpp_ror1(s[4 + j]);
            const float rAq = dpp_ror1(q[j]),     rBq = dpp_ror1(q[4 + j]);
            WA[j - 1] = is0 ? rBs : rAs;          // pred(A_0) = B_63
            WB[j - 1] = is0 ? rAs : rBs;          // pred(B_0) = A_63
            QA[j - 1] = is0 ? rBq : rAq;
            QB[j - 1] = is0 ? rAq : rBq;
        }
        #pragma unroll
        for (int j = 0; j < 4; ++j) {
            WA[3 + j] = s[j];     QA[3 + j] = q[j];
            WB[3 + j] = s[4 + j]; QB[3 + j] = q[4 + j];
        }
        #pragma unroll
        for (int j = 0; j <= 2; ++j) {            // successors
            const float rAs = dpp_rol1(s[j]),     rBs = dpp_rol1(s[4 + j]);
            const float rAq = dpp_rol1(q[j]),     rBq = dpp_rol1(q[4 + j]);
            WA[7 + j] = is63 ? rBs : rAs;         // succ(A_63) = B_0
            WB[7 + j] = is63 ? rAs : rBs;         // succ(B_63) = A_0 (wrap mod 512)
            QA[7 + j] = is63 ? rBq : rAq;
            QB[7 + j] = is63 ? rAq : rBq;
        }

        float res[8];
        {   // chunkA outputs (cols 4L .. 4L+3)
            float hs = WA[0]+WA[1]+WA[2]+WA[3]+WA[4]+WA[5]+WA[6];
            float hq = QA[0]+QA[1]+QA[2]+QA[3]+QA[4]+QA[5]+QA[6];
            { const float m = hs * inv; res[0] = fmaf(-m, m, hq * inv); }
            #pragma unroll
            for (int k = 1; k < 4; ++k) {
                hs += WA[k + 6] - WA[k - 1];
                hq += QA[k + 6] - QA[k - 1];
                const float m = hs * inv;
                res[k] = fmaf(-m, m, hq * inv);
            }
        }
        {   // chunkB outputs (cols 256+4L .. 256+4L+3)
            float hs = WB[0]+WB[1]+WB[2]+WB[3]+WB[4]+WB[5]+WB[6];
            float hq = QB[0]+QB[1]+QB[2]+QB[3]+QB[4]+QB[5]+QB[6];
            { const float m = hs * inv; res[4] = fmaf(-m, m, hq * inv); }
            #pragma unroll
            for (int k = 1; k < 4; ++k) {
                hs += WB[k + 6] - WB[k - 1];
                hq += QB[k + 6] - QB[k - 1];
                const float m = hs * inv;
                res[4 + k] = fmaf(-m, m, hq * inv);
            }
        }
        float* rowp = oim + r * W;
        f32x4 oA = {res[0], res[1], res[2], res[3]};
        f32x4 oB = {res[4], res[5], res[6], res[7]};
        *(f32x4*)(rowp + c4)       = oA;          // plain store: L2/L3 write-allocate
        *(f32x4*)(rowp + 256 + c4) = oB;
    };

    // ---- consume in load order; rows r1..r6 die at their acc ----
    acc(r0); acc(r1); acc(r2); acc(r3); acc(r4); acc(r5); acc(r6);
    emit(R);
    #pragma unroll
    for (int c = 0; c < 8; ++c) {                 // slide: +row R+4, -row R-3
        s[c] += r7[c] - r0[c];
        q[c] = fmaf(r7[c], r7[c], q[c]);
        q[c] = fmaf(-r0[c], r0[c], q[c]);
    }
    emit(R + 1);
}

extern "C" void kernel_launch(void* const* d_in, const int* in_sizes, int n_in,
                              void* d_out, int out_size, void* d_ws, size_t ws_size,
                              hipStream_t stream) {
    const float* x = (const float*)d_in[0];
    float* out = (float*)d_out;
    const int nimg = in_sizes[0] / (H * W);       // 48
    dim3 grid(nimg * 64);                         // 3072 blocks (8 | 3072)
    dim3 block(64, 4);
    lvar_kernel<<<grid, block, 0, stream>>>(x, out);
}